// Round 9
// baseline (528.567 us; speedup 1.0000x reference)
//
#include <hip/hip_runtime.h>

typedef __attribute__((ext_vector_type(8))) short bfrag;
typedef __attribute__((ext_vector_type(4))) float ffrag;

__device__ __forceinline__ ushort f2bf(float f) {
    union { float f; unsigned u; } v{f};
    unsigned r = v.u + 0x7fff + ((v.u >> 16) & 1);  // RNE
    return (ushort)(r >> 16);
}
__device__ __forceinline__ float bf2f(ushort u) {
    union { unsigned u; float f; } v{(unsigned)u << 16};
    return v.f;
}

// ---------------- utility ----------------

__global__ __launch_bounds__(256) void zero_kernel(int* __restrict__ p, int n) {
    int i = blockIdx.x * 256 + threadIdx.x;
    if (i < n) p[i] = 0;
}

// ---------------- CSR build: LDS bucket histogram -> scan -> two-pass radix placement ----------------

__global__ __launch_bounds__(256) void bhist(const int* __restrict__ dst, int* __restrict__ bcount) {
    __shared__ int h[256];
    const int t = threadIdx.x;
    h[t] = 0;
    __syncthreads();
    const int base = blockIdx.x * 4096;
#pragma unroll
    for (int u = 0; u < 16; ++u)
        atomicAdd(&h[((unsigned)dst[base + u * 256 + t]) >> 8], 1);
    __syncthreads();
    atomicAdd(&bcount[t], h[t]);
}

__global__ __launch_bounds__(256) void bscan(const int* __restrict__ bcount, int* __restrict__ bstart,
                                             int* __restrict__ bcursor) {
    __shared__ int s[256];
    const int t = threadIdx.x;
    int c = bcount[t];
    s[t] = c;
    __syncthreads();
    for (int o = 1; o < 256; o <<= 1) {
        int add = (t >= o) ? s[t - o] : 0;
        __syncthreads();
        s[t] += add;
        __syncthreads();
    }
    int excl = s[t] - c;
    bstart[t] = excl;
    bcursor[t] = excl;
    if (t == 255) bstart[256] = s[t];
}

#define CH 4096

__global__ __launch_bounds__(256) void bucket1(const int* __restrict__ src, const int* __restrict__ dst,
                                               const float* __restrict__ w, int* __restrict__ bcursor,
                                               int2* __restrict__ staged) {
    __shared__ int cnt_s[256], base_l[256], base_g[256], cur[256];
    __shared__ int2 stage[CH];
    __shared__ unsigned char bb[CH];
    const int t = threadIdx.x;
    const int base = blockIdx.x * CH;
    cnt_s[t] = 0;
    __syncthreads();
#pragma unroll
    for (int u = 0; u < CH / 256; ++u) {
        int b = ((unsigned)dst[base + u * 256 + t]) >> 8;
        atomicAdd(&cnt_s[b], 1);
    }
    __syncthreads();
    int v = cnt_s[t];
    base_l[t] = v;
    __syncthreads();
    for (int o = 1; o < 256; o <<= 1) {
        int add = (t >= o) ? base_l[t - o] : 0;
        __syncthreads();
        base_l[t] += add;
        __syncthreads();
    }
    int excl = base_l[t] - v;
    base_l[t] = excl;
    cur[t] = excl;
    base_g[t] = atomicAdd(&bcursor[t], v);
    __syncthreads();
#pragma unroll
    for (int u = 0; u < CH / 256; ++u) {
        int e = base + u * 256 + t;
        int d = dst[e];
        int b = ((unsigned)d) >> 8;
        int p = atomicAdd(&cur[b], 1);
        stage[p] = make_int2((src[e] & 0xffff) | ((d & 255) << 16), __float_as_int(w[e]));
        bb[p] = (unsigned char)b;
    }
    __syncthreads();
    for (int i = t; i < CH; i += 256) {
        int b = bb[i];
        staged[base_g[b] + (i - base_l[b])] = stage[i];
    }
}

__global__ __launch_bounds__(256) void bucket2n(const int* __restrict__ bstart, const int2* __restrict__ staged,
                                                int* __restrict__ start, int2* __restrict__ edges) {
    __shared__ int cnt[256], excl[256], cur[256];
    const int t = threadIdx.x;
    const int b = blockIdx.x;
    cnt[t] = 0;
    __syncthreads();
    const int s0 = bstart[b];
    const int s1 = bstart[b + 1];
    for (int i = s0 + t; i < s1; i += 256) {
        int dl = (staged[i].x >> 16) & 0xff;
        atomicAdd(&cnt[dl], 1);
    }
    __syncthreads();
    int v = cnt[t];
    excl[t] = v;
    __syncthreads();
    for (int o = 1; o < 256; o <<= 1) {
        int add = (t >= o) ? excl[t - o] : 0;
        __syncthreads();
        excl[t] += add;
        __syncthreads();
    }
    int e = excl[t] - v;
    cur[t] = e;
    start[b * 256 + t] = s0 + e;
    if (b == 255 && t == 255) start[256 * 256] = s1;
    __syncthreads();
    for (int i = s0 + t; i < s1; i += 256) {
        int2 se = staged[i];
        int dl = (se.x >> 16) & 0xff;
        int p = s0 + atomicAdd(&cur[dl], 1);
        edges[p] = make_int2(se.x & 0xffff, se.y);
    }
}

// ---------------- weight prep: fp32 [k][n] -> bf16 transposed [n][k], 6 matrices ----------------

__global__ __launch_bounds__(256) void wprep(const float* __restrict__ Wb_in, const float* __restrict__ Wl_in,
                                             const float* __restrict__ W_base, const float* __restrict__ W_local,
                                             ushort* __restrict__ out) {
    int idx = blockIdx.x * 256 + threadIdx.x;
    int mat = idx >> 14;
    int i = idx & 16383;
    int nn = i >> 7, kk = i & 127;
    const float* src;
    switch (mat) {
        case 0: src = Wb_in; break;
        case 1: src = Wl_in; break;
        case 2: src = W_base; break;
        case 3: src = W_base + 16384; break;
        case 4: src = W_local; break;
        default: src = W_local + 16384; break;
    }
    out[(size_t)mat * 16384 + i] = f2bf(src[kk * 128 + nn]);
}

#define ASTRIDE 136  // ushort stride: 272B rows, 16B-aligned

// ---------------- input-projection GEMM (fp32 A -> bf16 Y), LDS-staged ----------------

__global__ __launch_bounds__(256) void gemm_in(const float* __restrict__ A, const ushort* __restrict__ Wt,
                                               const float* __restrict__ bias, ushort* __restrict__ Y) {
    __shared__ ushort As[64 * ASTRIDE];
    const int tid = threadIdx.x;
    const int r0 = blockIdx.x * 64;

#pragma unroll
    for (int p = 0; p < 8; ++p) {
        int c = p * 256 + tid;
        int row = c >> 5, o4 = (c & 31) * 4;
        float4 v = *(const float4*)(A + (size_t)(r0 + row) * 128 + o4);
        ushort4 u;
        u.x = f2bf(v.x); u.y = f2bf(v.y); u.z = f2bf(v.z); u.w = f2bf(v.w);
        *(ushort4*)&As[row * ASTRIDE + o4] = u;
    }
    __syncthreads();

    const int lane = tid & 63;
    const int w = tid >> 6;
    const int wm = (w & 1) * 32;
    const int wn = (w >> 1) * 64;
    const int q = lane >> 4;
    const int l16 = lane & 15;

    ffrag acc[2][4];
#pragma unroll
    for (int mt = 0; mt < 2; ++mt)
#pragma unroll
        for (int nt = 0; nt < 4; ++nt) acc[mt][nt] = (ffrag){0.f, 0.f, 0.f, 0.f};

#pragma unroll
    for (int kc = 0; kc < 4; ++kc) {
        bfrag a[2], b[4];
#pragma unroll
        for (int mt = 0; mt < 2; ++mt)
            a[mt] = *(const bfrag*)&As[(wm + mt * 16 + l16) * ASTRIDE + kc * 32 + q * 8];
#pragma unroll
        for (int nt = 0; nt < 4; ++nt)
            b[nt] = *(const bfrag*)(Wt + (wn + nt * 16 + l16) * 128 + kc * 32 + q * 8);
#pragma unroll
        for (int mt = 0; mt < 2; ++mt)
#pragma unroll
            for (int nt = 0; nt < 4; ++nt)
                acc[mt][nt] = __builtin_amdgcn_mfma_f32_16x16x32_bf16(a[mt], b[nt], acc[mt][nt], 0, 0, 0);
    }

    float bias_v[4];
#pragma unroll
    for (int nt = 0; nt < 4; ++nt) bias_v[nt] = bias[wn + nt * 16 + l16];
#pragma unroll
    for (int mt = 0; mt < 2; ++mt)
#pragma unroll
        for (int nt = 0; nt < 4; ++nt)
#pragma unroll
            for (int r = 0; r < 4; ++r) {
                int row = r0 + wm + mt * 16 + q * 4 + r;
                int col = wn + nt * 16 + l16;
                float v = fmaxf(acc[mt][nt][r] + bias_v[nt], 0.f);
                Y[(size_t)row * 128 + col] = f2bf(v);
            }
}

// ---------------- FUSED: SpMM gather -> (mix) -> MFMA GEMM -> relu -> Y(bf16) ----------------
// Block = 64 dst nodes. Phase 1: 8 half-waves gather/accumulate edges (proven spmm loop),
// fp32 mix, bf16 into As. Phase 2: MFMA with B-fragments read directly from global Wt (L2-hot).

template <bool MIX>
__global__ __launch_bounds__(256) void spmm_gemm(const int* __restrict__ start, const int2* __restrict__ edges,
                                                 const ushort* __restrict__ X, const ushort* __restrict__ A2,
                                                 const int* __restrict__ ridx, const ushort* __restrict__ Wt,
                                                 const float* __restrict__ bias, ushort* __restrict__ Y) {
    __shared__ ushort As[64 * ASTRIDE];
    const int tid = threadIdx.x;
    const int r0 = blockIdx.x * 64;
    const int sw = tid >> 5;       // 8 half-waves
    const int lane = tid & 31;
    const int f = lane * 4;

#pragma unroll
    for (int i = 0; i < 8; ++i) {
        const int node = r0 + i * 8 + sw;
        const int rl = i * 8 + sw;
        int s0 = start[node];
        int s1 = start[node + 1];
        float a0 = 0.f, a1 = 0.f, a2 = 0.f, a3 = 0.f;
        int e = s0;
        for (; e + 4 <= s1; e += 4) {
            int2 e0 = edges[e + 0], e1 = edges[e + 1], e2 = edges[e + 2], e3 = edges[e + 3];
            float w0 = __int_as_float(e0.y), w1 = __int_as_float(e1.y);
            float w2 = __int_as_float(e2.y), w3 = __int_as_float(e3.y);
            ushort4 v0 = *(const ushort4*)(X + (size_t)e0.x * 128 + f);
            ushort4 v1 = *(const ushort4*)(X + (size_t)e1.x * 128 + f);
            ushort4 v2 = *(const ushort4*)(X + (size_t)e2.x * 128 + f);
            ushort4 v3 = *(const ushort4*)(X + (size_t)e3.x * 128 + f);
            a0 += w0 * bf2f(v0.x) + w1 * bf2f(v1.x) + w2 * bf2f(v2.x) + w3 * bf2f(v3.x);
            a1 += w0 * bf2f(v0.y) + w1 * bf2f(v1.y) + w2 * bf2f(v2.y) + w3 * bf2f(v3.y);
            a2 += w0 * bf2f(v0.z) + w1 * bf2f(v1.z) + w2 * bf2f(v2.z) + w3 * bf2f(v3.z);
            a3 += w0 * bf2f(v0.w) + w1 * bf2f(v1.w) + w2 * bf2f(v2.w) + w3 * bf2f(v3.w);
        }
        for (; e < s1; ++e) {
            int2 ee = edges[e];
            float w = __int_as_float(ee.y);
            ushort4 v = *(const ushort4*)(X + (size_t)ee.x * 128 + f);
            a0 += w * bf2f(v.x);
            a1 += w * bf2f(v.y);
            a2 += w * bf2f(v.z);
            a3 += w * bf2f(v.w);
        }
        if (MIX) {
            int rr = ridx[node];
            ushort4 m = *(const ushort4*)(A2 + (size_t)rr * 128 + f);
            a0 = 0.9f * a0 + 0.1f * bf2f(m.x);
            a1 = 0.9f * a1 + 0.1f * bf2f(m.y);
            a2 = 0.9f * a2 + 0.1f * bf2f(m.z);
            a3 = 0.9f * a3 + 0.1f * bf2f(m.w);
        }
        ushort4 o;
        o.x = f2bf(a0);
        o.y = f2bf(a1);
        o.z = f2bf(a2);
        o.w = f2bf(a3);
        *(ushort4*)&As[rl * ASTRIDE + f] = o;
    }
    __syncthreads();

    const int wlane = tid & 63;
    const int w = tid >> 6;
    const int wm = (w & 1) * 32;
    const int wn = (w >> 1) * 64;
    const int q = wlane >> 4;
    const int l16 = wlane & 15;

    ffrag acc[2][4];
#pragma unroll
    for (int mt = 0; mt < 2; ++mt)
#pragma unroll
        for (int nt = 0; nt < 4; ++nt) acc[mt][nt] = (ffrag){0.f, 0.f, 0.f, 0.f};

#pragma unroll
    for (int kc = 0; kc < 4; ++kc) {
        bfrag a[2], b[4];
#pragma unroll
        for (int mt = 0; mt < 2; ++mt)
            a[mt] = *(const bfrag*)&As[(wm + mt * 16 + l16) * ASTRIDE + kc * 32 + q * 8];
#pragma unroll
        for (int nt = 0; nt < 4; ++nt)
            b[nt] = *(const bfrag*)(Wt + (wn + nt * 16 + l16) * 128 + kc * 32 + q * 8);
#pragma unroll
        for (int mt = 0; mt < 2; ++mt)
#pragma unroll
            for (int nt = 0; nt < 4; ++nt)
                acc[mt][nt] = __builtin_amdgcn_mfma_f32_16x16x32_bf16(a[mt], b[nt], acc[mt][nt], 0, 0, 0);
    }

    float bias_v[4];
#pragma unroll
    for (int nt = 0; nt < 4; ++nt) bias_v[nt] = bias[wn + nt * 16 + l16];
#pragma unroll
    for (int mt = 0; mt < 2; ++mt)
#pragma unroll
        for (int nt = 0; nt < 4; ++nt)
#pragma unroll
            for (int r = 0; r < 4; ++r) {
                int row = r0 + wm + mt * 16 + q * 4 + r;
                int col = wn + nt * 16 + l16;
                float v = fmaxf(acc[mt][nt][r] + bias_v[nt], 0.f);
                Y[(size_t)row * 128 + col] = f2bf(v);
            }
}

// ---------------- pooling: counting sort by gid, then register-accumulated segment sums ----------------

__global__ __launch_bounds__(256) void pool_hist(const int* __restrict__ memb_gid, int* __restrict__ gcount) {
    __shared__ int h[64];
    int t = threadIdx.x;
    if (t < 64) h[t] = 0;
    __syncthreads();
    int base = blockIdx.x * 1024;
#pragma unroll
    for (int u = 0; u < 4; ++u) atomicAdd(&h[memb_gid[base + u * 256 + t]], 1);
    __syncthreads();
    if (t < 64) atomicAdd(&gcount[t], h[t]);
}

__global__ __launch_bounds__(64) void pool_scan(const int* __restrict__ gcount, int* __restrict__ gstart,
                                                int* __restrict__ cursor) {
    __shared__ int s[64];
    int t = threadIdx.x;
    int c = gcount[t];
    s[t] = c;
    __syncthreads();
    int acc = 0;
    for (int j = 0; j < 64; ++j)
        if (j < t) acc += s[j];
    gstart[t] = acc;
    cursor[t] = acc;
    if (t == 63) gstart[64] = acc + c;
}

__global__ __launch_bounds__(256) void pool_scatter(const int* __restrict__ memb_idx,
                                                    const int* __restrict__ memb_gid,
                                                    int* __restrict__ cursor, int* __restrict__ sorted_idx) {
    __shared__ int lhist[64];
    __shared__ int lbase[64];
    __shared__ int loff[1024];
    int t = threadIdx.x;
    if (t < 64) lhist[t] = 0;
    __syncthreads();
    int base = blockIdx.x * 1024;
    int g[4], ix[4];
#pragma unroll
    for (int u = 0; u < 4; ++u) {
        int e = base + u * 256 + t;
        g[u] = memb_gid[e];
        ix[u] = memb_idx[e];
        loff[u * 256 + t] = atomicAdd(&lhist[g[u]], 1);
    }
    __syncthreads();
    if (t < 64) lbase[t] = atomicAdd(&cursor[t], lhist[t]);
    __syncthreads();
#pragma unroll
    for (int u = 0; u < 4; ++u) {
        int pos = lbase[g[u]] + loff[u * 256 + t];
        sorted_idx[pos] = ix[u];
    }
}

__global__ __launch_bounds__(256) void pool_accum(const int* __restrict__ gstart, const int* __restrict__ sorted_idx,
                                                  const ushort* __restrict__ X, float* __restrict__ gsum) {
    const int g = blockIdx.x >> 5;
    const int sgm = blockIdx.x & 31;
    const int gs = gstart[g];
    const int cnt = gstart[g + 1] - gs;
    const int e_begin = gs + ((cnt * sgm) >> 5);
    const int e_end = gs + ((cnt * (sgm + 1)) >> 5);
    const int t = threadIdx.x;
    const int fp = t & 63;
    const int sub = t >> 6;
    float ax = 0.f, ay = 0.f;
#pragma unroll 4
    for (int e = e_begin + sub; e < e_end; e += 4) {
        int idx = sorted_idx[e];
        ushort2 u = *(const ushort2*)(X + (size_t)idx * 128 + fp * 2);
        ax += bf2f(u.x);
        ay += bf2f(u.y);
    }
    __shared__ float sx[256], sy[256];
    sx[t] = ax;
    sy[t] = ay;
    __syncthreads();
    if (t < 64) {
        atomicAdd(&gsum[g * 128 + fp * 2 + 0], sx[t] + sx[t + 64] + sx[t + 128] + sx[t + 192]);
        atomicAdd(&gsum[g * 128 + fp * 2 + 1], sy[t] + sy[t + 64] + sy[t + 128] + sy[t + 192]);
    }
}

// ---------------- final: out = (gsum/cnt) @ Wp + bp, 64x2 ----------------

__global__ __launch_bounds__(128) void final_kernel(const float* __restrict__ gsum, const int* __restrict__ gcnt,
                                                    const float* __restrict__ Wp, const float* __restrict__ bp,
                                                    float* __restrict__ out) {
    int t = threadIdx.x;
    int g = t >> 1;
    int o = t & 1;
    float inv = 1.f / fmaxf((float)gcnt[g], 1.f);
    float acc = bp[o];
    for (int f = 0; f < 128; ++f) acc += gsum[g * 128 + f] * inv * Wp[f * 2 + o];
    out[g * 2 + o] = acc;
}

// ---------------- launch ----------------

extern "C" void kernel_launch(void* const* d_in, const int* in_sizes, int n_in,
                              void* d_out, int out_size, void* d_ws, size_t ws_size,
                              hipStream_t stream) {
    const float* x              = (const float*)d_in[0];
    const int*   edge_index     = (const int*)d_in[1];
    const float* edge_weight    = (const float*)d_in[2];
    const float* local_x0       = (const float*)d_in[3];
    const int*   copy2orig      = (const int*)d_in[4];
    const int*   local_adj_idx  = (const int*)d_in[5];
    const float* local_adj_val  = (const float*)d_in[6];
    const int*   memb_idx       = (const int*)d_in[7];
    const int*   memb_gid       = (const int*)d_in[8];
    const float* Wb_in          = (const float*)d_in[10];
    const float* bb_in          = (const float*)d_in[11];
    const float* Wl_in          = (const float*)d_in[12];
    const float* bl_in          = (const float*)d_in[13];
    const float* W_base         = (const float*)d_in[14];
    const float* b_base         = (const float*)d_in[15];
    const float* W_local        = (const float*)d_in[16];
    const float* b_local        = (const float*)d_in[17];
    const float* Wp             = (const float*)d_in[18];
    const float* bp             = (const float*)d_in[19];
    float* out = (float*)d_out;

    constexpr int N = 65536, M = 65536, E = 1048576, EL = 1048576, K = 131072, H = 128;

    char* wsb = (char*)d_ws;
    size_t off = 0;
    auto alloc = [&](size_t bytes) -> char* {
        char* p = wsb + off;
        off += (bytes + 255) & ~(size_t)255;
        return p;
    };
    int*    bs_start = (int*)alloc((size_t)(N + 1) * 4);
    int2*   bs_edges = (int2*)alloc((size_t)E * 8);
    int2*   bs_stage = (int2*)alloc((size_t)E * 8);
    int*    bs_bcnt  = (int*)alloc(256 * 4);
    int*    bs_bsta  = (int*)alloc(257 * 4);
    int*    bs_bcur  = (int*)alloc(256 * 4);
    int*    ls_start = (int*)alloc((size_t)(M + 1) * 4);
    int2*   ls_edges = (int2*)alloc((size_t)EL * 8);
    int2*   ls_stage = (int2*)alloc((size_t)EL * 8);
    int*    ls_bcnt  = (int*)alloc(256 * 4);
    int*    ls_bsta  = (int*)alloc(257 * 4);
    int*    ls_bcur  = (int*)alloc(256 * 4);
    ushort* bufA     = (ushort*)alloc((size_t)N * H * 2);
    ushort* bufB     = (ushort*)alloc((size_t)M * H * 2);
    ushort* bufC     = (ushort*)alloc((size_t)N * H * 2);
    ushort* bufD     = (ushort*)alloc((size_t)M * H * 2);
    ushort* wt       = (ushort*)alloc((size_t)6 * 16384 * 2);
    int*    p_gcnt   = (int*)alloc(64 * 4);
    int*    p_gstart = (int*)alloc(65 * 4);
    int*    p_cursor = (int*)alloc(64 * 4);
    int*    p_sorted = (int*)alloc((size_t)K * 4);
    float*  pool_sum = (float*)alloc(64 * 128 * 4);

    const int* b_src = edge_index;
    const int* b_dst = edge_index + E;
    const int* l_src = local_adj_idx;
    const int* l_dst = local_adj_idx + EL;

    // zero counters / accumulators
    zero_kernel<<<1, 256, 0, stream>>>(bs_bcnt, 256);
    zero_kernel<<<1, 256, 0, stream>>>(ls_bcnt, 256);
    zero_kernel<<<1, 256, 0, stream>>>(p_gcnt, 64);
    zero_kernel<<<32, 256, 0, stream>>>((int*)pool_sum, 64 * 128);

    // weight prep (bf16 transposed)
    wprep<<<384, 256, 0, stream>>>(Wb_in, Wl_in, W_base, W_local, wt);

    // CSR build (base graph)
    bhist<<<E / 4096, 256, 0, stream>>>(b_dst, bs_bcnt);
    bscan<<<1, 256, 0, stream>>>(bs_bcnt, bs_bsta, bs_bcur);
    bucket1<<<E / CH, 256, 0, stream>>>(b_src, b_dst, edge_weight, bs_bcur, bs_stage);
    bucket2n<<<256, 256, 0, stream>>>(bs_bsta, bs_stage, bs_start, bs_edges);

    // CSR build (local graph)
    bhist<<<EL / 4096, 256, 0, stream>>>(l_dst, ls_bcnt);
    bscan<<<1, 256, 0, stream>>>(ls_bcnt, ls_bsta, ls_bcur);
    bucket1<<<EL / CH, 256, 0, stream>>>(l_src, l_dst, local_adj_val, ls_bcur, ls_stage);
    bucket2n<<<256, 256, 0, stream>>>(ls_bsta, ls_stage, ls_start, ls_edges);

    // sort membership entries by gid
    pool_hist<<<K / 1024, 256, 0, stream>>>(memb_gid, p_gcnt);
    pool_scan<<<1, 64, 0, stream>>>(p_gcnt, p_gstart, p_cursor);
    pool_scatter<<<K / 1024, 256, 0, stream>>>(memb_idx, memb_gid, p_cursor, p_sorted);

    // input projections
    gemm_in<<<N / 64, 256, 0, stream>>>(x, wt, bb_in, bufA);
    gemm_in<<<M / 64, 256, 0, stream>>>(local_x0, wt + 16384, bl_in, bufB);

    // layer 0: base A->C, local B->D (mix with C)
    spmm_gemm<false><<<N / 64, 256, 0, stream>>>(bs_start, bs_edges, bufA, nullptr, nullptr,
                                                 wt + 2 * 16384, b_base, bufC);
    spmm_gemm<true><<<M / 64, 256, 0, stream>>>(ls_start, ls_edges, bufB, bufC, copy2orig,
                                                wt + 4 * 16384, b_local, bufD);
    // layer 1: base C->A, local D->B (mix with A)
    spmm_gemm<false><<<N / 64, 256, 0, stream>>>(bs_start, bs_edges, bufC, nullptr, nullptr,
                                                 wt + 3 * 16384, b_base + H, bufA);
    spmm_gemm<true><<<M / 64, 256, 0, stream>>>(ls_start, ls_edges, bufD, bufA, copy2orig,
                                                wt + 5 * 16384, b_local + H, bufB);

    // pooling + final projection
    pool_accum<<<64 * 32, 256, 0, stream>>>(p_gstart, p_sorted, bufB, pool_sum);
    final_kernel<<<1, 128, 0, stream>>>(pool_sum, p_gcnt, Wp, bp, out);
}

// Round 10
// 510.575 us; speedup vs baseline: 1.0352x; 1.0352x over previous
//
#include <hip/hip_runtime.h>

typedef __attribute__((ext_vector_type(8))) short bfrag;
typedef __attribute__((ext_vector_type(4))) float ffrag;

__device__ __forceinline__ ushort f2bf(float f) {
    union { float f; unsigned u; } v{f};
    unsigned r = v.u + 0x7fff + ((v.u >> 16) & 1);  // RNE
    return (ushort)(r >> 16);
}
__device__ __forceinline__ float bf2f(ushort u) {
    union { unsigned u; float f; } v{(unsigned)u << 16};
    return v.f;
}

// ---------------- utility ----------------

__global__ __launch_bounds__(256) void zero_all(int* __restrict__ a, int* __restrict__ b,
                                                int* __restrict__ c, int* __restrict__ d) {
    int i = blockIdx.x * 256 + threadIdx.x;
    if (i < 256) { a[i] = 0; b[i] = 0; }
    if (i < 64) c[i] = 0;
    if (i < 64 * 128) d[i] = 0;
}

// ---------------- CSR build: LDS bucket histogram -> scan -> two-pass radix placement ----------------

__global__ __launch_bounds__(256) void bhist(const int* __restrict__ dst, int* __restrict__ bcount) {
    __shared__ int h[256];
    const int t = threadIdx.x;
    h[t] = 0;
    __syncthreads();
    const int base = blockIdx.x * 4096;
#pragma unroll
    for (int u = 0; u < 16; ++u)
        atomicAdd(&h[((unsigned)dst[base + u * 256 + t]) >> 8], 1);
    __syncthreads();
    atomicAdd(&bcount[t], h[t]);
}

__global__ __launch_bounds__(256) void bscan(const int* __restrict__ bcount, int* __restrict__ bstart,
                                             int* __restrict__ bcursor) {
    __shared__ int s[256];
    const int t = threadIdx.x;
    int c = bcount[t];
    s[t] = c;
    __syncthreads();
    for (int o = 1; o < 256; o <<= 1) {
        int add = (t >= o) ? s[t - o] : 0;
        __syncthreads();
        s[t] += add;
        __syncthreads();
    }
    int excl = s[t] - c;
    bstart[t] = excl;
    bcursor[t] = excl;
    if (t == 255) bstart[256] = s[t];
}

#define CH 2048  // edges per block in pass 1 (512 blocks -> 2 blocks/CU, LDS ~18KB)

__global__ __launch_bounds__(256) void bucket1(const int* __restrict__ src, const int* __restrict__ dst,
                                               const float* __restrict__ w, int* __restrict__ bcursor,
                                               int2* __restrict__ staged) {
    __shared__ int cnt_s[256], base_l[256], base_g[256], cur[256];
    __shared__ int2 stage[CH];
    __shared__ unsigned char bb[CH];
    const int t = threadIdx.x;
    const int base = blockIdx.x * CH;
    cnt_s[t] = 0;
    __syncthreads();
#pragma unroll
    for (int u = 0; u < CH / 256; ++u) {
        int b = ((unsigned)dst[base + u * 256 + t]) >> 8;
        atomicAdd(&cnt_s[b], 1);
    }
    __syncthreads();
    int v = cnt_s[t];
    base_l[t] = v;
    __syncthreads();
    for (int o = 1; o < 256; o <<= 1) {
        int add = (t >= o) ? base_l[t - o] : 0;
        __syncthreads();
        base_l[t] += add;
        __syncthreads();
    }
    int excl = base_l[t] - v;
    base_l[t] = excl;
    cur[t] = excl;
    base_g[t] = atomicAdd(&bcursor[t], v);
    __syncthreads();
#pragma unroll
    for (int u = 0; u < CH / 256; ++u) {
        int e = base + u * 256 + t;
        int d = dst[e];
        int b = ((unsigned)d) >> 8;
        int p = atomicAdd(&cur[b], 1);
        stage[p] = make_int2((src[e] & 0xffff) | ((d & 255) << 16), __float_as_int(w[e]));
        bb[p] = (unsigned char)b;
    }
    __syncthreads();
    for (int i = t; i < CH; i += 256) {
        int b = bb[i];
        staged[base_g[b] + (i - base_l[b])] = stage[i];
    }
}

__global__ __launch_bounds__(256) void bucket2n(const int* __restrict__ bstart, const int2* __restrict__ staged,
                                                int* __restrict__ start, int2* __restrict__ edges) {
    __shared__ int cnt[256], excl[256], cur[256];
    const int t = threadIdx.x;
    const int b = blockIdx.x;
    cnt[t] = 0;
    __syncthreads();
    const int s0 = bstart[b];
    const int s1 = bstart[b + 1];
    for (int i = s0 + t; i < s1; i += 256) {
        int dl = (staged[i].x >> 16) & 0xff;
        atomicAdd(&cnt[dl], 1);
    }
    __syncthreads();
    int v = cnt[t];
    excl[t] = v;
    __syncthreads();
    for (int o = 1; o < 256; o <<= 1) {
        int add = (t >= o) ? excl[t - o] : 0;
        __syncthreads();
        excl[t] += add;
        __syncthreads();
    }
    int e = excl[t] - v;
    cur[t] = e;
    start[b * 256 + t] = s0 + e;
    if (b == 255 && t == 255) start[256 * 256] = s1;
    __syncthreads();
    for (int i = s0 + t; i < s1; i += 256) {
        int2 se = staged[i];
        int dl = (se.x >> 16) & 0xff;
        int p = s0 + atomicAdd(&cur[dl], 1);
        edges[p] = make_int2(se.x & 0xffff, se.y);
    }
}

// ---------------- weight prep: fp32 [k][n] -> bf16 transposed [n][k], 6 matrices ----------------

__global__ __launch_bounds__(256) void wprep(const float* __restrict__ Wb_in, const float* __restrict__ Wl_in,
                                             const float* __restrict__ W_base, const float* __restrict__ W_local,
                                             ushort* __restrict__ out) {
    int idx = blockIdx.x * 256 + threadIdx.x;
    int mat = idx >> 14;
    int i = idx & 16383;
    int nn = i >> 7, kk = i & 127;
    const float* src;
    switch (mat) {
        case 0: src = Wb_in; break;
        case 1: src = Wl_in; break;
        case 2: src = W_base; break;
        case 3: src = W_base + 16384; break;
        case 4: src = W_local; break;
        default: src = W_local + 16384; break;
    }
    out[(size_t)mat * 16384 + i] = f2bf(src[kk * 128 + nn]);
}

#define ASTRIDE 136  // ushort stride: 272B rows, 16B-aligned

// ---------------- MFMA GEMM: Y(bf16) = relu(A_eff @ W + bias) ----------------
// A staged in LDS (bf16); B-fragments read directly from global Wt (32KB, L2-hot, 1024x reuse).
// Block: 256 threads (4 waves), 64 rows x 128 cols. LDS 17KB -> high occupancy.

template <bool A_F32, bool MIX>
__global__ __launch_bounds__(256) void gemm_mfma(const void* __restrict__ Ap, const ushort* __restrict__ A2,
                                                 const int* __restrict__ ridx,
                                                 const ushort* __restrict__ Wt, const float* __restrict__ bias,
                                                 ushort* __restrict__ Y) {
    __shared__ ushort As[64 * ASTRIDE];
    const int tid = threadIdx.x;
    const int r0 = blockIdx.x * 64;

    if (A_F32) {
        const float* A = (const float*)Ap;
#pragma unroll
        for (int p = 0; p < 8; ++p) {
            int c = p * 256 + tid;
            int row = c >> 5, o4 = (c & 31) * 4;
            float4 v = *(const float4*)(A + (size_t)(r0 + row) * 128 + o4);
            ushort4 u;
            u.x = f2bf(v.x); u.y = f2bf(v.y); u.z = f2bf(v.z); u.w = f2bf(v.w);
            *(ushort4*)&As[row * ASTRIDE + o4] = u;
        }
    } else {
        const ushort* A = (const ushort*)Ap;
#pragma unroll
        for (int p = 0; p < 4; ++p) {
            int c = p * 256 + tid;
            int row = c >> 4, o8 = (c & 15) * 8;
            uint4 v = *(const uint4*)(A + (size_t)(r0 + row) * 128 + o8);
            if (MIX) {
                int rr = ridx[r0 + row];
                uint4 v2 = *(const uint4*)(A2 + (size_t)rr * 128 + o8);
                uint4 o;
                float x0, x1;
                x0 = 0.9f * bf2f((ushort)(v.x & 0xffff)) + 0.1f * bf2f((ushort)(v2.x & 0xffff));
                x1 = 0.9f * bf2f((ushort)(v.x >> 16)) + 0.1f * bf2f((ushort)(v2.x >> 16));
                o.x = (unsigned)f2bf(x0) | ((unsigned)f2bf(x1) << 16);
                x0 = 0.9f * bf2f((ushort)(v.y & 0xffff)) + 0.1f * bf2f((ushort)(v2.y & 0xffff));
                x1 = 0.9f * bf2f((ushort)(v.y >> 16)) + 0.1f * bf2f((ushort)(v2.y >> 16));
                o.y = (unsigned)f2bf(x0) | ((unsigned)f2bf(x1) << 16);
                x0 = 0.9f * bf2f((ushort)(v.z & 0xffff)) + 0.1f * bf2f((ushort)(v2.z & 0xffff));
                x1 = 0.9f * bf2f((ushort)(v.z >> 16)) + 0.1f * bf2f((ushort)(v2.z >> 16));
                o.z = (unsigned)f2bf(x0) | ((unsigned)f2bf(x1) << 16);
                x0 = 0.9f * bf2f((ushort)(v.w & 0xffff)) + 0.1f * bf2f((ushort)(v2.w & 0xffff));
                x1 = 0.9f * bf2f((ushort)(v.w >> 16)) + 0.1f * bf2f((ushort)(v2.w >> 16));
                o.w = (unsigned)f2bf(x0) | ((unsigned)f2bf(x1) << 16);
                v = o;
            }
            *(uint4*)&As[row * ASTRIDE + o8] = v;
        }
    }
    __syncthreads();

    const int lane = tid & 63;
    const int w = tid >> 6;
    const int wm = (w & 1) * 32;
    const int wn = (w >> 1) * 64;
    const int q = lane >> 4;
    const int l16 = lane & 15;

    ffrag acc[2][4];
#pragma unroll
    for (int mt = 0; mt < 2; ++mt)
#pragma unroll
        for (int nt = 0; nt < 4; ++nt) acc[mt][nt] = (ffrag){0.f, 0.f, 0.f, 0.f};

#pragma unroll
    for (int kc = 0; kc < 4; ++kc) {
        bfrag a[2], b[4];
#pragma unroll
        for (int mt = 0; mt < 2; ++mt)
            a[mt] = *(const bfrag*)&As[(wm + mt * 16 + l16) * ASTRIDE + kc * 32 + q * 8];
#pragma unroll
        for (int nt = 0; nt < 4; ++nt)
            b[nt] = *(const bfrag*)(Wt + (wn + nt * 16 + l16) * 128 + kc * 32 + q * 8);
#pragma unroll
        for (int mt = 0; mt < 2; ++mt)
#pragma unroll
            for (int nt = 0; nt < 4; ++nt)
                acc[mt][nt] = __builtin_amdgcn_mfma_f32_16x16x32_bf16(a[mt], b[nt], acc[mt][nt], 0, 0, 0);
    }

    float bias_v[4];
#pragma unroll
    for (int nt = 0; nt < 4; ++nt) bias_v[nt] = bias[wn + nt * 16 + l16];
#pragma unroll
    for (int mt = 0; mt < 2; ++mt)
#pragma unroll
        for (int nt = 0; nt < 4; ++nt)
#pragma unroll
            for (int r = 0; r < 4; ++r) {
                int row = r0 + wm + mt * 16 + q * 4 + r;
                int col = wn + nt * 16 + l16;
                float v = fmaxf(acc[mt][nt][r] + bias_v[nt], 0.f);
                Y[(size_t)row * 128 + col] = f2bf(v);
            }
}

// ---------------- SpMM: half-wave (32 lanes) per dst node, ushort4/lane, 4-edge unroll ----------------

__global__ __launch_bounds__(256) void spmm_bf16(const int* __restrict__ start, const int2* __restrict__ edges,
                                                 const ushort* __restrict__ X, ushort* __restrict__ Y, int n) {
    int node = (blockIdx.x * 256 + threadIdx.x) >> 5;
    int lane = threadIdx.x & 31;
    if (node >= n) return;
    int s0 = start[node];
    int s1 = start[node + 1];
    const int f = lane * 4;
    float a0 = 0.f, a1 = 0.f, a2 = 0.f, a3 = 0.f;
    int e = s0;
    for (; e + 4 <= s1; e += 4) {
        int2 e0 = edges[e + 0], e1 = edges[e + 1], e2 = edges[e + 2], e3 = edges[e + 3];
        float w0 = __int_as_float(e0.y), w1 = __int_as_float(e1.y);
        float w2 = __int_as_float(e2.y), w3 = __int_as_float(e3.y);
        ushort4 v0 = *(const ushort4*)(X + (size_t)e0.x * 128 + f);
        ushort4 v1 = *(const ushort4*)(X + (size_t)e1.x * 128 + f);
        ushort4 v2 = *(const ushort4*)(X + (size_t)e2.x * 128 + f);
        ushort4 v3 = *(const ushort4*)(X + (size_t)e3.x * 128 + f);
        a0 += w0 * bf2f(v0.x) + w1 * bf2f(v1.x) + w2 * bf2f(v2.x) + w3 * bf2f(v3.x);
        a1 += w0 * bf2f(v0.y) + w1 * bf2f(v1.y) + w2 * bf2f(v2.y) + w3 * bf2f(v3.y);
        a2 += w0 * bf2f(v0.z) + w1 * bf2f(v1.z) + w2 * bf2f(v2.z) + w3 * bf2f(v3.z);
        a3 += w0 * bf2f(v0.w) + w1 * bf2f(v1.w) + w2 * bf2f(v2.w) + w3 * bf2f(v3.w);
    }
    for (; e < s1; ++e) {
        int2 ee = edges[e];
        float w = __int_as_float(ee.y);
        ushort4 v = *(const ushort4*)(X + (size_t)ee.x * 128 + f);
        a0 += w * bf2f(v.x);
        a1 += w * bf2f(v.y);
        a2 += w * bf2f(v.z);
        a3 += w * bf2f(v.w);
    }
    ushort4 o;
    o.x = f2bf(a0);
    o.y = f2bf(a1);
    o.z = f2bf(a2);
    o.w = f2bf(a3);
    *(ushort4*)(Y + (size_t)node * 128 + f) = o;
}

// ---------------- pooling: counting sort by gid, then register-accumulated segment sums ----------------

__global__ __launch_bounds__(256) void pool_hist(const int* __restrict__ memb_gid, int* __restrict__ gcount) {
    __shared__ int h[64];
    int t = threadIdx.x;
    if (t < 64) h[t] = 0;
    __syncthreads();
    int base = blockIdx.x * 1024;
#pragma unroll
    for (int u = 0; u < 4; ++u) atomicAdd(&h[memb_gid[base + u * 256 + t]], 1);
    __syncthreads();
    if (t < 64) atomicAdd(&gcount[t], h[t]);
}

__global__ __launch_bounds__(64) void pool_scan(const int* __restrict__ gcount, int* __restrict__ gstart,
                                                int* __restrict__ cursor) {
    __shared__ int s[64];
    int t = threadIdx.x;
    int c = gcount[t];
    s[t] = c;
    __syncthreads();
    int acc = 0;
    for (int j = 0; j < 64; ++j)
        if (j < t) acc += s[j];
    gstart[t] = acc;
    cursor[t] = acc;
    if (t == 63) gstart[64] = acc + c;
}

__global__ __launch_bounds__(256) void pool_scatter(const int* __restrict__ memb_idx,
                                                    const int* __restrict__ memb_gid,
                                                    int* __restrict__ cursor, int* __restrict__ sorted_idx) {
    __shared__ int lhist[64];
    __shared__ int lbase[64];
    __shared__ int loff[1024];
    int t = threadIdx.x;
    if (t < 64) lhist[t] = 0;
    __syncthreads();
    int base = blockIdx.x * 1024;
    int g[4], ix[4];
#pragma unroll
    for (int u = 0; u < 4; ++u) {
        int e = base + u * 256 + t;
        g[u] = memb_gid[e];
        ix[u] = memb_idx[e];
        loff[u * 256 + t] = atomicAdd(&lhist[g[u]], 1);
    }
    __syncthreads();
    if (t < 64) lbase[t] = atomicAdd(&cursor[t], lhist[t]);
    __syncthreads();
#pragma unroll
    for (int u = 0; u < 4; ++u) {
        int pos = lbase[g[u]] + loff[u * 256 + t];
        sorted_idx[pos] = ix[u];
    }
}

__global__ __launch_bounds__(256) void pool_accum(const int* __restrict__ gstart, const int* __restrict__ sorted_idx,
                                                  const ushort* __restrict__ X, float* __restrict__ gsum) {
    const int g = blockIdx.x >> 5;
    const int sgm = blockIdx.x & 31;
    const int gs = gstart[g];
    const int cnt = gstart[g + 1] - gs;
    const int e_begin = gs + ((cnt * sgm) >> 5);
    const int e_end = gs + ((cnt * (sgm + 1)) >> 5);
    const int t = threadIdx.x;
    const int fp = t & 63;
    const int sub = t >> 6;
    float ax = 0.f, ay = 0.f;
#pragma unroll 4
    for (int e = e_begin + sub; e < e_end; e += 4) {
        int idx = sorted_idx[e];
        ushort2 u = *(const ushort2*)(X + (size_t)idx * 128 + fp * 2);
        ax += bf2f(u.x);
        ay += bf2f(u.y);
    }
    __shared__ float sx[256], sy[256];
    sx[t] = ax;
    sy[t] = ay;
    __syncthreads();
    if (t < 64) {
        atomicAdd(&gsum[g * 128 + fp * 2 + 0], sx[t] + sx[t + 64] + sx[t + 128] + sx[t + 192]);
        atomicAdd(&gsum[g * 128 + fp * 2 + 1], sy[t] + sy[t + 64] + sy[t + 128] + sy[t + 192]);
    }
}

// ---------------- final: out = (gsum/cnt) @ Wp + bp, 64x2 ----------------

__global__ __launch_bounds__(128) void final_kernel(const float* __restrict__ gsum, const int* __restrict__ gcnt,
                                                    const float* __restrict__ Wp, const float* __restrict__ bp,
                                                    float* __restrict__ out) {
    int t = threadIdx.x;
    int g = t >> 1;
    int o = t & 1;
    float inv = 1.f / fmaxf((float)gcnt[g], 1.f);
    float acc = bp[o];
    for (int f = 0; f < 128; ++f) acc += gsum[g * 128 + f] * inv * Wp[f * 2 + o];
    out[g * 2 + o] = acc;
}

// ---------------- launch ----------------

extern "C" void kernel_launch(void* const* d_in, const int* in_sizes, int n_in,
                              void* d_out, int out_size, void* d_ws, size_t ws_size,
                              hipStream_t stream) {
    const float* x              = (const float*)d_in[0];
    const int*   edge_index     = (const int*)d_in[1];
    const float* edge_weight    = (const float*)d_in[2];
    const float* local_x0       = (const float*)d_in[3];
    const int*   copy2orig      = (const int*)d_in[4];
    const int*   local_adj_idx  = (const int*)d_in[5];
    const float* local_adj_val  = (const float*)d_in[6];
    const int*   memb_idx       = (const int*)d_in[7];
    const int*   memb_gid       = (const int*)d_in[8];
    const float* Wb_in          = (const float*)d_in[10];
    const float* bb_in          = (const float*)d_in[11];
    const float* Wl_in          = (const float*)d_in[12];
    const float* bl_in          = (const float*)d_in[13];
    const float* W_base         = (const float*)d_in[14];
    const float* b_base         = (const float*)d_in[15];
    const float* W_local        = (const float*)d_in[16];
    const float* b_local        = (const float*)d_in[17];
    const float* Wp             = (const float*)d_in[18];
    const float* bp             = (const float*)d_in[19];
    float* out = (float*)d_out;

    constexpr int N = 65536, M = 65536, E = 1048576, EL = 1048576, K = 131072, H = 128;

    char* wsb = (char*)d_ws;
    size_t off = 0;
    auto alloc = [&](size_t bytes) -> char* {
        char* p = wsb + off;
        off += (bytes + 255) & ~(size_t)255;
        return p;
    };
    int*    bs_start = (int*)alloc((size_t)(N + 1) * 4);
    int2*   bs_edges = (int2*)alloc((size_t)E * 8);
    int2*   bs_stage = (int2*)alloc((size_t)E * 8);
    int*    bs_bcnt  = (int*)alloc(256 * 4);
    int*    bs_bsta  = (int*)alloc(257 * 4);
    int*    bs_bcur  = (int*)alloc(256 * 4);
    int*    ls_start = (int*)alloc((size_t)(M + 1) * 4);
    int2*   ls_edges = (int2*)alloc((size_t)EL * 8);
    int2*   ls_stage = (int2*)alloc((size_t)EL * 8);
    int*    ls_bcnt  = (int*)alloc(256 * 4);
    int*    ls_bsta  = (int*)alloc(257 * 4);
    int*    ls_bcur  = (int*)alloc(256 * 4);
    ushort* bufA     = (ushort*)alloc((size_t)N * H * 2);
    ushort* bufB     = (ushort*)alloc((size_t)M * H * 2);
    ushort* bufC     = (ushort*)alloc((size_t)N * H * 2);
    ushort* bufD     = (ushort*)alloc((size_t)M * H * 2);
    ushort* wt       = (ushort*)alloc((size_t)6 * 16384 * 2);
    int*    p_gcnt   = (int*)alloc(64 * 4);
    int*    p_gstart = (int*)alloc(65 * 4);
    int*    p_cursor = (int*)alloc(64 * 4);
    int*    p_sorted = (int*)alloc((size_t)K * 4);
    float*  pool_sum = (float*)alloc(64 * 128 * 4);

    const int* b_src = edge_index;
    const int* b_dst = edge_index + E;
    const int* l_src = local_adj_idx;
    const int* l_dst = local_adj_idx + EL;

    // zero counters / accumulators (one dispatch)
    zero_all<<<32, 256, 0, stream>>>(bs_bcnt, ls_bcnt, p_gcnt, (int*)pool_sum);

    // weight prep (bf16 transposed)
    wprep<<<384, 256, 0, stream>>>(Wb_in, Wl_in, W_base, W_local, wt);

    // CSR build (base graph)
    bhist<<<E / 4096, 256, 0, stream>>>(b_dst, bs_bcnt);
    bscan<<<1, 256, 0, stream>>>(bs_bcnt, bs_bsta, bs_bcur);
    bucket1<<<E / CH, 256, 0, stream>>>(b_src, b_dst, edge_weight, bs_bcur, bs_stage);
    bucket2n<<<256, 256, 0, stream>>>(bs_bsta, bs_stage, bs_start, bs_edges);

    // CSR build (local graph)
    bhist<<<EL / 4096, 256, 0, stream>>>(l_dst, ls_bcnt);
    bscan<<<1, 256, 0, stream>>>(ls_bcnt, ls_bsta, ls_bcur);
    bucket1<<<EL / CH, 256, 0, stream>>>(l_src, l_dst, local_adj_val, ls_bcur, ls_stage);
    bucket2n<<<256, 256, 0, stream>>>(ls_bsta, ls_stage, ls_start, ls_edges);

    // sort membership entries by gid
    pool_hist<<<K / 1024, 256, 0, stream>>>(memb_gid, p_gcnt);
    pool_scan<<<1, 64, 0, stream>>>(p_gcnt, p_gstart, p_cursor);
    pool_scatter<<<K / 1024, 256, 0, stream>>>(memb_idx, memb_gid, p_cursor, p_sorted);

    // input projections (fp32 A -> bf16 out)
    gemm_mfma<true, false><<<N / 64, 256, 0, stream>>>(x, nullptr, nullptr, wt, bb_in, bufA);
    gemm_mfma<true, false><<<M / 64, 256, 0, stream>>>(local_x0, nullptr, nullptr, wt + 16384, bl_in, bufB);

    // layers
    for (int l = 0; l < 2; ++l) {
        spmm_bf16<<<N * 32 / 256, 256, 0, stream>>>(bs_start, bs_edges, bufA, bufC, N);
        spmm_bf16<<<M * 32 / 256, 256, 0, stream>>>(ls_start, ls_edges, bufB, bufD, M);
        gemm_mfma<false, false><<<N / 64, 256, 0, stream>>>(bufC, nullptr, nullptr,
                                                            wt + (size_t)(2 + l) * 16384, b_base + (size_t)l * H, bufA);
        gemm_mfma<false, true><<<M / 64, 256, 0, stream>>>(bufD, bufA, copy2orig,
                                                           wt + (size_t)(4 + l) * 16384, b_local + (size_t)l * H, bufB);
    }

    // pooling + final projection
    pool_accum<<<64 * 32, 256, 0, stream>>>(p_gstart, p_sorted, bufB, pool_sum);
    final_kernel<<<1, 128, 0, stream>>>(pool_sum, p_gcnt, Wp, bp, out);
}

// Round 11
// 465.068 us; speedup vs baseline: 1.1365x; 1.0978x over previous
//
#include <hip/hip_runtime.h>

typedef __attribute__((ext_vector_type(8))) short bfrag;
typedef __attribute__((ext_vector_type(4))) float ffrag;

__device__ __forceinline__ ushort f2bf(float f) {
    union { float f; unsigned u; } v{f};
    unsigned r = v.u + 0x7fff + ((v.u >> 16) & 1);  // RNE
    return (ushort)(r >> 16);
}
__device__ __forceinline__ float bf2f(ushort u) {
    union { unsigned u; float f; } v{(unsigned)u << 16};
    return v.f;
}
__device__ __forceinline__ float bflo(unsigned u) {
    union { unsigned u; float f; } v{u << 16};
    return v.f;
}
__device__ __forceinline__ float bfhi(unsigned u) {
    union { unsigned u; float f; } v{u & 0xffff0000u};
    return v.f;
}

// ---------------- utility ----------------

__global__ __launch_bounds__(256) void zero_all(int* __restrict__ a, int* __restrict__ b,
                                                int* __restrict__ c, int* __restrict__ d) {
    int i = blockIdx.x * 256 + threadIdx.x;
    if (i < 256) { a[i] = 0; b[i] = 0; }
    if (i < 64) c[i] = 0;
    if (i < 64 * 128) d[i] = 0;
}

// ---------------- CSR build: LDS bucket histogram -> scan -> two-pass radix placement ----------------
// Bucket = dst>>8. bucket1/bucket2n use 1024 threads: grid=256 -> 1 block/CU, 16 waves each.

__global__ __launch_bounds__(256) void bhist(const int* __restrict__ dst, int* __restrict__ bcount) {
    __shared__ int h[256];
    const int t = threadIdx.x;
    h[t] = 0;
    __syncthreads();
    const int base = blockIdx.x * 4096;
#pragma unroll
    for (int u = 0; u < 16; ++u)
        atomicAdd(&h[((unsigned)dst[base + u * 256 + t]) >> 8], 1);
    __syncthreads();
    atomicAdd(&bcount[t], h[t]);
}

__global__ __launch_bounds__(256) void bscan(const int* __restrict__ bcount, int* __restrict__ bstart,
                                             int* __restrict__ bcursor) {
    __shared__ int s[256];
    const int t = threadIdx.x;
    int c = bcount[t];
    s[t] = c;
    __syncthreads();
    for (int o = 1; o < 256; o <<= 1) {
        int add = (t >= o) ? s[t - o] : 0;
        __syncthreads();
        s[t] += add;
        __syncthreads();
    }
    int excl = s[t] - c;
    bstart[t] = excl;
    bcursor[t] = excl;
    if (t == 255) bstart[256] = s[t];
}

#define CH 4096  // edges per block in pass 1 (256 blocks, 1024 threads each)

__global__ __launch_bounds__(1024) void bucket1(const int* __restrict__ src, const int* __restrict__ dst,
                                                const float* __restrict__ w, int* __restrict__ bcursor,
                                                int2* __restrict__ staged) {
    __shared__ int cnt_s[256], base_l[256], base_g[256], cur[256];
    __shared__ int2 stage[CH];
    __shared__ unsigned char bb[CH];
    const int t = threadIdx.x;
    const int base = blockIdx.x * CH;
    if (t < 256) cnt_s[t] = 0;
    __syncthreads();
#pragma unroll
    for (int u = 0; u < CH / 1024; ++u) {
        int b = ((unsigned)dst[base + u * 1024 + t]) >> 8;
        atomicAdd(&cnt_s[b], 1);
    }
    __syncthreads();
    int v = 0;
    if (t < 256) { v = cnt_s[t]; base_l[t] = v; }
    __syncthreads();
    for (int o = 1; o < 256; o <<= 1) {
        int add = 0;
        if (t < 256 && t >= o) add = base_l[t - o];
        __syncthreads();
        if (t < 256) base_l[t] += add;
        __syncthreads();
    }
    if (t < 256) {
        int excl = base_l[t] - v;
        base_l[t] = excl;
        cur[t] = excl;
        base_g[t] = atomicAdd(&bcursor[t], v);
    }
    __syncthreads();
#pragma unroll
    for (int u = 0; u < CH / 1024; ++u) {
        int e = base + u * 1024 + t;
        int d = dst[e];
        int b = ((unsigned)d) >> 8;
        int p = atomicAdd(&cur[b], 1);
        stage[p] = make_int2((src[e] & 0xffff) | ((d & 255) << 16), __float_as_int(w[e]));
        bb[p] = (unsigned char)b;
    }
    __syncthreads();
    for (int i = t; i < CH; i += 1024) {
        int b = bb[i];
        staged[base_g[b] + (i - base_l[b])] = stage[i];
    }
}

// per bucket: node-level LDS histogram + scan -> start[] (coalesced), then place edges
__global__ __launch_bounds__(1024) void bucket2n(const int* __restrict__ bstart, const int2* __restrict__ staged,
                                                 int* __restrict__ start, int2* __restrict__ edges) {
    __shared__ int cnt[256], excl[256], cur[256];
    const int t = threadIdx.x;
    const int b = blockIdx.x;
    if (t < 256) cnt[t] = 0;
    __syncthreads();
    const int s0 = bstart[b];
    const int s1 = bstart[b + 1];
    for (int i = s0 + t; i < s1; i += 1024) {
        int dl = (staged[i].x >> 16) & 0xff;
        atomicAdd(&cnt[dl], 1);
    }
    __syncthreads();
    int v = 0;
    if (t < 256) { v = cnt[t]; excl[t] = v; }
    __syncthreads();
    for (int o = 1; o < 256; o <<= 1) {
        int add = 0;
        if (t < 256 && t >= o) add = excl[t - o];
        __syncthreads();
        if (t < 256) excl[t] += add;
        __syncthreads();
    }
    if (t < 256) {
        int e = excl[t] - v;
        cur[t] = e;
        start[b * 256 + t] = s0 + e;
        if (b == 255 && t == 255) start[256 * 256] = s1;
    }
    __syncthreads();
    for (int i = s0 + t; i < s1; i += 1024) {
        int2 se = staged[i];
        int dl = (se.x >> 16) & 0xff;
        int p = s0 + atomicAdd(&cur[dl], 1);
        edges[p] = make_int2(se.x & 0xffff, se.y);
    }
}

// ---------------- weight prep: fp32 [k][n] -> bf16 transposed [n][k], 6 matrices ----------------

__global__ __launch_bounds__(256) void wprep(const float* __restrict__ Wb_in, const float* __restrict__ Wl_in,
                                             const float* __restrict__ W_base, const float* __restrict__ W_local,
                                             ushort* __restrict__ out) {
    int idx = blockIdx.x * 256 + threadIdx.x;
    int mat = idx >> 14;
    int i = idx & 16383;
    int nn = i >> 7, kk = i & 127;
    const float* src;
    switch (mat) {
        case 0: src = Wb_in; break;
        case 1: src = Wl_in; break;
        case 2: src = W_base; break;
        case 3: src = W_base + 16384; break;
        case 4: src = W_local; break;
        default: src = W_local + 16384; break;
    }
    out[(size_t)mat * 16384 + i] = f2bf(src[kk * 128 + nn]);
}

#define ASTRIDE 136  // ushort stride: 272B rows, 16B-aligned

// ---------------- MFMA GEMM (R8-proven): A and B staged in LDS ----------------

template <bool A_F32, bool MIX>
__global__ __launch_bounds__(256) void gemm_mfma(const void* __restrict__ Ap, const ushort* __restrict__ A2,
                                                 const int* __restrict__ ridx,
                                                 const ushort* __restrict__ Wt, const float* __restrict__ bias,
                                                 ushort* __restrict__ Y) {
    __shared__ ushort As[64 * ASTRIDE];
    __shared__ ushort Bs[128 * ASTRIDE];
    const int tid = threadIdx.x;
    const int r0 = blockIdx.x * 64;

    if (A_F32) {
        const float* A = (const float*)Ap;
#pragma unroll
        for (int p = 0; p < 8; ++p) {
            int c = p * 256 + tid;
            int row = c >> 5, o4 = (c & 31) * 4;
            float4 v = *(const float4*)(A + (size_t)(r0 + row) * 128 + o4);
            ushort4 u;
            u.x = f2bf(v.x); u.y = f2bf(v.y); u.z = f2bf(v.z); u.w = f2bf(v.w);
            *(ushort4*)&As[row * ASTRIDE + o4] = u;
        }
    } else {
        const ushort* A = (const ushort*)Ap;
#pragma unroll
        for (int p = 0; p < 4; ++p) {
            int c = p * 256 + tid;
            int row = c >> 4, o8 = (c & 15) * 8;
            uint4 v = *(const uint4*)(A + (size_t)(r0 + row) * 128 + o8);
            if (MIX) {
                int rr = ridx[r0 + row];
                uint4 v2 = *(const uint4*)(A2 + (size_t)rr * 128 + o8);
                uint4 o;
                float x0, x1;
                x0 = 0.9f * bflo(v.x) + 0.1f * bflo(v2.x);
                x1 = 0.9f * bfhi(v.x) + 0.1f * bfhi(v2.x);
                o.x = (unsigned)f2bf(x0) | ((unsigned)f2bf(x1) << 16);
                x0 = 0.9f * bflo(v.y) + 0.1f * bflo(v2.y);
                x1 = 0.9f * bfhi(v.y) + 0.1f * bfhi(v2.y);
                o.y = (unsigned)f2bf(x0) | ((unsigned)f2bf(x1) << 16);
                x0 = 0.9f * bflo(v.z) + 0.1f * bflo(v2.z);
                x1 = 0.9f * bfhi(v.z) + 0.1f * bfhi(v2.z);
                o.z = (unsigned)f2bf(x0) | ((unsigned)f2bf(x1) << 16);
                x0 = 0.9f * bflo(v.w) + 0.1f * bflo(v2.w);
                x1 = 0.9f * bfhi(v.w) + 0.1f * bfhi(v2.w);
                o.w = (unsigned)f2bf(x0) | ((unsigned)f2bf(x1) << 16);
                v = o;
            }
            *(uint4*)&As[row * ASTRIDE + o8] = v;
        }
    }
#pragma unroll
    for (int p = 0; p < 8; ++p) {
        int c = p * 256 + tid;
        int n = c >> 4, o8 = (c & 15) * 8;
        *(uint4*)&Bs[n * ASTRIDE + o8] = *(const uint4*)(Wt + n * 128 + o8);
    }
    __syncthreads();

    const int lane = tid & 63;
    const int w = tid >> 6;
    const int wm = (w & 1) * 32;
    const int wn = (w >> 1) * 64;
    const int q = lane >> 4;
    const int l16 = lane & 15;

    ffrag acc[2][4];
#pragma unroll
    for (int mt = 0; mt < 2; ++mt)
#pragma unroll
        for (int nt = 0; nt < 4; ++nt) acc[mt][nt] = (ffrag){0.f, 0.f, 0.f, 0.f};

#pragma unroll
    for (int kc = 0; kc < 4; ++kc) {
        bfrag a[2], b[4];
#pragma unroll
        for (int mt = 0; mt < 2; ++mt)
            a[mt] = *(const bfrag*)&As[(wm + mt * 16 + l16) * ASTRIDE + kc * 32 + q * 8];
#pragma unroll
        for (int nt = 0; nt < 4; ++nt)
            b[nt] = *(const bfrag*)&Bs[(wn + nt * 16 + l16) * ASTRIDE + kc * 32 + q * 8];
#pragma unroll
        for (int mt = 0; mt < 2; ++mt)
#pragma unroll
            for (int nt = 0; nt < 4; ++nt)
                acc[mt][nt] = __builtin_amdgcn_mfma_f32_16x16x32_bf16(a[mt], b[nt], acc[mt][nt], 0, 0, 0);
    }

    float bias_v[4];
#pragma unroll
    for (int nt = 0; nt < 4; ++nt) bias_v[nt] = bias[wn + nt * 16 + l16];
#pragma unroll
    for (int mt = 0; mt < 2; ++mt)
#pragma unroll
        for (int nt = 0; nt < 4; ++nt)
#pragma unroll
            for (int r = 0; r < 4; ++r) {
                int row = r0 + wm + mt * 16 + q * 4 + r;
                int col = wn + nt * 16 + l16;
                float v = fmaxf(acc[mt][nt][r] + bias_v[nt], 0.f);
                Y[(size_t)row * 128 + col] = f2bf(v);
            }
}

// ---------------- SpMM: half-wave (32 lanes) per dst node, ushort4/lane, 4-edge unroll ----------------

__global__ __launch_bounds__(256) void spmm_bf16(const int* __restrict__ start, const int2* __restrict__ edges,
                                                 const ushort* __restrict__ X, ushort* __restrict__ Y, int n) {
    int node = (blockIdx.x * 256 + threadIdx.x) >> 5;
    int lane = threadIdx.x & 31;
    if (node >= n) return;
    int s0 = start[node];
    int s1 = start[node + 1];
    const int f = lane * 4;
    float a0 = 0.f, a1 = 0.f, a2 = 0.f, a3 = 0.f;
    int e = s0;
    for (; e + 4 <= s1; e += 4) {
        int2 e0 = edges[e + 0], e1 = edges[e + 1], e2 = edges[e + 2], e3 = edges[e + 3];
        float w0 = __int_as_float(e0.y), w1 = __int_as_float(e1.y);
        float w2 = __int_as_float(e2.y), w3 = __int_as_float(e3.y);
        ushort4 v0 = *(const ushort4*)(X + (size_t)e0.x * 128 + f);
        ushort4 v1 = *(const ushort4*)(X + (size_t)e1.x * 128 + f);
        ushort4 v2 = *(const ushort4*)(X + (size_t)e2.x * 128 + f);
        ushort4 v3 = *(const ushort4*)(X + (size_t)e3.x * 128 + f);
        a0 += w0 * bf2f(v0.x) + w1 * bf2f(v1.x) + w2 * bf2f(v2.x) + w3 * bf2f(v3.x);
        a1 += w0 * bf2f(v0.y) + w1 * bf2f(v1.y) + w2 * bf2f(v2.y) + w3 * bf2f(v3.y);
        a2 += w0 * bf2f(v0.z) + w1 * bf2f(v1.z) + w2 * bf2f(v2.z) + w3 * bf2f(v3.z);
        a3 += w0 * bf2f(v0.w) + w1 * bf2f(v1.w) + w2 * bf2f(v2.w) + w3 * bf2f(v3.w);
    }
    for (; e < s1; ++e) {
        int2 ee = edges[e];
        float w = __int_as_float(ee.y);
        ushort4 v = *(const ushort4*)(X + (size_t)ee.x * 128 + f);
        a0 += w * bf2f(v.x);
        a1 += w * bf2f(v.y);
        a2 += w * bf2f(v.z);
        a3 += w * bf2f(v.w);
    }
    ushort4 o;
    o.x = f2bf(a0);
    o.y = f2bf(a1);
    o.z = f2bf(a2);
    o.w = f2bf(a3);
    *(ushort4*)(Y + (size_t)node * 128 + f) = o;
}

// ---------------- pooling: counting sort by gid, then register-accumulated segment sums ----------------

__global__ __launch_bounds__(256) void pool_hist(const int* __restrict__ memb_gid, int* __restrict__ gcount) {
    __shared__ int h[64];
    int t = threadIdx.x;
    if (t < 64) h[t] = 0;
    __syncthreads();
    int base = blockIdx.x * 1024;
#pragma unroll
    for (int u = 0; u < 4; ++u) atomicAdd(&h[memb_gid[base + u * 256 + t]], 1);
    __syncthreads();
    if (t < 64) atomicAdd(&gcount[t], h[t]);
}

__global__ __launch_bounds__(64) void pool_scan(const int* __restrict__ gcount, int* __restrict__ gstart,
                                                int* __restrict__ cursor) {
    __shared__ int s[64];
    int t = threadIdx.x;
    int c = gcount[t];
    s[t] = c;
    __syncthreads();
    int acc = 0;
    for (int j = 0; j < 64; ++j)
        if (j < t) acc += s[j];
    gstart[t] = acc;
    cursor[t] = acc;
    if (t == 63) gstart[64] = acc + c;
}

__global__ __launch_bounds__(256) void pool_scatter(const int* __restrict__ memb_idx,
                                                    const int* __restrict__ memb_gid,
                                                    int* __restrict__ cursor, int* __restrict__ sorted_idx) {
    __shared__ int lhist[64];
    __shared__ int lbase[64];
    __shared__ int loff[1024];
    int t = threadIdx.x;
    if (t < 64) lhist[t] = 0;
    __syncthreads();
    int base = blockIdx.x * 1024;
    int g[4], ix[4];
#pragma unroll
    for (int u = 0; u < 4; ++u) {
        int e = base + u * 256 + t;
        g[u] = memb_gid[e];
        ix[u] = memb_idx[e];
        loff[u * 256 + t] = atomicAdd(&lhist[g[u]], 1);
    }
    __syncthreads();
    if (t < 64) lbase[t] = atomicAdd(&cursor[t], lhist[t]);
    __syncthreads();
#pragma unroll
    for (int u = 0; u < 4; ++u) {
        int pos = lbase[g[u]] + loff[u * 256 + t];
        sorted_idx[pos] = ix[u];
    }
}

__global__ __launch_bounds__(256) void pool_accum(const int* __restrict__ gstart, const int* __restrict__ sorted_idx,
                                                  const ushort* __restrict__ X, float* __restrict__ gsum) {
    const int g = blockIdx.x >> 5;
    const int sgm = blockIdx.x & 31;
    const int gs = gstart[g];
    const int cnt = gstart[g + 1] - gs;
    const int e_begin = gs + ((cnt * sgm) >> 5);
    const int e_end = gs + ((cnt * (sgm + 1)) >> 5);
    const int t = threadIdx.x;
    const int fp = t & 63;
    const int sub = t >> 6;
    float ax = 0.f, ay = 0.f;
#pragma unroll 4
    for (int e = e_begin + sub; e < e_end; e += 4) {
        int idx = sorted_idx[e];
        ushort2 u = *(const ushort2*)(X + (size_t)idx * 128 + fp * 2);
        ax += bf2f(u.x);
        ay += bf2f(u.y);
    }
    __shared__ float sx[256], sy[256];
    sx[t] = ax;
    sy[t] = ay;
    __syncthreads();
    if (t < 64) {
        atomicAdd(&gsum[g * 128 + fp * 2 + 0], sx[t] + sx[t + 64] + sx[t + 128] + sx[t + 192]);
        atomicAdd(&gsum[g * 128 + fp * 2 + 1], sy[t] + sy[t + 64] + sy[t + 128] + sy[t + 192]);
    }
}

// ---------------- final: out = (gsum/cnt) @ Wp + bp, 64x2 ----------------

__global__ __launch_bounds__(128) void final_kernel(const float* __restrict__ gsum, const int* __restrict__ gcnt,
                                                    const float* __restrict__ Wp, const float* __restrict__ bp,
                                                    float* __restrict__ out) {
    int t = threadIdx.x;
    int g = t >> 1;
    int o = t & 1;
    float inv = 1.f / fmaxf((float)gcnt[g], 1.f);
    float acc = bp[o];
    for (int f = 0; f < 128; ++f) acc += gsum[g * 128 + f] * inv * Wp[f * 2 + o];
    out[g * 2 + o] = acc;
}

// ---------------- launch ----------------

extern "C" void kernel_launch(void* const* d_in, const int* in_sizes, int n_in,
                              void* d_out, int out_size, void* d_ws, size_t ws_size,
                              hipStream_t stream) {
    const float* x              = (const float*)d_in[0];
    const int*   edge_index     = (const int*)d_in[1];
    const float* edge_weight    = (const float*)d_in[2];
    const float* local_x0       = (const float*)d_in[3];
    const int*   copy2orig      = (const int*)d_in[4];
    const int*   local_adj_idx  = (const int*)d_in[5];
    const float* local_adj_val  = (const float*)d_in[6];
    const int*   memb_idx       = (const int*)d_in[7];
    const int*   memb_gid       = (const int*)d_in[8];
    const float* Wb_in          = (const float*)d_in[10];
    const float* bb_in          = (const float*)d_in[11];
    const float* Wl_in          = (const float*)d_in[12];
    const float* bl_in          = (const float*)d_in[13];
    const float* W_base         = (const float*)d_in[14];
    const float* b_base         = (const float*)d_in[15];
    const float* W_local        = (const float*)d_in[16];
    const float* b_local        = (const float*)d_in[17];
    const float* Wp             = (const float*)d_in[18];
    const float* bp             = (const float*)d_in[19];
    float* out = (float*)d_out;

    constexpr int N = 65536, M = 65536, E = 1048576, EL = 1048576, K = 131072, H = 128;

    char* wsb = (char*)d_ws;
    size_t off = 0;
    auto alloc = [&](size_t bytes) -> char* {
        char* p = wsb + off;
        off += (bytes + 255) & ~(size_t)255;
        return p;
    };
    int*    bs_start = (int*)alloc((size_t)(N + 1) * 4);
    int2*   bs_edges = (int2*)alloc((size_t)E * 8);
    int2*   bs_stage = (int2*)alloc((size_t)E * 8);
    int*    bs_bcnt  = (int*)alloc(256 * 4);
    int*    bs_bsta  = (int*)alloc(257 * 4);
    int*    bs_bcur  = (int*)alloc(256 * 4);
    int*    ls_start = (int*)alloc((size_t)(M + 1) * 4);
    int2*   ls_edges = (int2*)alloc((size_t)EL * 8);
    int2*   ls_stage = (int2*)alloc((size_t)EL * 8);
    int*    ls_bcnt  = (int*)alloc(256 * 4);
    int*    ls_bsta  = (int*)alloc(257 * 4);
    int*    ls_bcur  = (int*)alloc(256 * 4);
    ushort* bufA     = (ushort*)alloc((size_t)N * H * 2);
    ushort* bufB     = (ushort*)alloc((size_t)M * H * 2);
    ushort* bufC     = (ushort*)alloc((size_t)N * H * 2);
    ushort* bufD     = (ushort*)alloc((size_t)M * H * 2);
    ushort* wt       = (ushort*)alloc((size_t)6 * 16384 * 2);
    int*    p_gcnt   = (int*)alloc(64 * 4);
    int*    p_gstart = (int*)alloc(65 * 4);
    int*    p_cursor = (int*)alloc(64 * 4);
    int*    p_sorted = (int*)alloc((size_t)K * 4);
    float*  pool_sum = (float*)alloc(64 * 128 * 4);

    const int* b_src = edge_index;
    const int* b_dst = edge_index + E;
    const int* l_src = local_adj_idx;
    const int* l_dst = local_adj_idx + EL;

    // zero counters / accumulators (one dispatch)
    zero_all<<<32, 256, 0, stream>>>(bs_bcnt, ls_bcnt, p_gcnt, (int*)pool_sum);

    // weight prep (bf16 transposed)
    wprep<<<384, 256, 0, stream>>>(Wb_in, Wl_in, W_base, W_local, wt);

    // CSR build (base graph)
    bhist<<<E / 4096, 256, 0, stream>>>(b_dst, bs_bcnt);
    bscan<<<1, 256, 0, stream>>>(bs_bcnt, bs_bsta, bs_bcur);
    bucket1<<<E / CH, 1024, 0, stream>>>(b_src, b_dst, edge_weight, bs_bcur, bs_stage);
    bucket2n<<<256, 1024, 0, stream>>>(bs_bsta, bs_stage, bs_start, bs_edges);

    // CSR build (local graph)
    bhist<<<EL / 4096, 256, 0, stream>>>(l_dst, ls_bcnt);
    bscan<<<1, 256, 0, stream>>>(ls_bcnt, ls_bsta, ls_bcur);
    bucket1<<<EL / CH, 1024, 0, stream>>>(l_src, l_dst, local_adj_val, ls_bcur, ls_stage);
    bucket2n<<<256, 1024, 0, stream>>>(ls_bsta, ls_stage, ls_start, ls_edges);

    // sort membership entries by gid
    pool_hist<<<K / 1024, 256, 0, stream>>>(memb_gid, p_gcnt);
    pool_scan<<<1, 64, 0, stream>>>(p_gcnt, p_gstart, p_cursor);
    pool_scatter<<<K / 1024, 256, 0, stream>>>(memb_idx, memb_gid, p_cursor, p_sorted);

    // input projections (fp32 A -> bf16 out)
    gemm_mfma<true, false><<<N / 64, 256, 0, stream>>>(x, nullptr, nullptr, wt, bb_in, bufA);
    gemm_mfma<true, false><<<M / 64, 256, 0, stream>>>(local_x0, nullptr, nullptr, wt + 16384, bl_in, bufB);

    // layers
    for (int l = 0; l < 2; ++l) {
        spmm_bf16<<<N * 32 / 256, 256, 0, stream>>>(bs_start, bs_edges, bufA, bufC, N);
        spmm_bf16<<<M * 32 / 256, 256, 0, stream>>>(ls_start, ls_edges, bufB, bufD, M);
        gemm_mfma<false, false><<<N / 64, 256, 0, stream>>>(bufC, nullptr, nullptr,
                                                            wt + (size_t)(2 + l) * 16384, b_base + (size_t)l * H, bufA);
        gemm_mfma<false, true><<<M / 64, 256, 0, stream>>>(bufD, bufA, copy2orig,
                                                           wt + (size_t)(4 + l) * 16384, b_local + (size_t)l * H, bufB);
    }

    // pooling + final projection
    pool_accum<<<64 * 32, 256, 0, stream>>>(p_gstart, p_sorted, bufB, pool_sum);
    final_kernel<<<1, 128, 0, stream>>>(pool_sum, p_gcnt, Wp, bp, out);
}